// Round 8
// baseline (3504.443 us; speedup 1.0000x reference)
//
#include <hip/hip_runtime.h>
#include <hip/hip_bf16.h>

#define N 4096
#define B 8
#define ITERS 10
#define T (ITERS * N)
#define NT 256          // 4 waves
#define E 16            // field elements per thread
#define WIN 1024
#define INFK 0xFFFFFFFFu
#define LIMIT 0x01000000u

// Kernel 1: Z0[b][i] = sum_j W[i][j] * x[b][j], accumulated in double.
// UNCHANGED (decision-identical trajectory vs rounds 1-7).
__global__ __launch_bounds__(256) void z0_gemv(const float* __restrict__ W,
                                               const float* __restrict__ x,
                                               double* __restrict__ Z0) {
    const int i = blockIdx.x;
    const int tid = threadIdx.x;
    const float* __restrict__ row = W + (size_t)i * N;

    double acc[B];
#pragma unroll
    for (int b = 0; b < B; ++b) acc[b] = 0.0;

    for (int j = tid; j < N; j += 256) {
        const double w = (double)row[j];
#pragma unroll
        for (int b = 0; b < B; ++b) acc[b] += w * (double)x[b * N + j];
    }

    __shared__ double red[256 * B];  // 16 KB
#pragma unroll
    for (int b = 0; b < B; ++b) red[tid * B + b] = acc[b];
    __syncthreads();

    for (int s = 128; s > 0; s >>= 1) {
        if (tid < s) {
#pragma unroll
            for (int b = 0; b < B; ++b) red[tid * B + b] += red[(tid + s) * B + b];
        }
        __syncthreads();
    }
    if (tid < B) Z0[(size_t)tid * N + i] = red[tid];
}

__device__ __forceinline__ unsigned umin2(unsigned a, unsigned b) { return a < b ? a : b; }

template <int CTRL>
__device__ __forceinline__ unsigned dpp_min(unsigned v) {
    const int t = __builtin_amdgcn_update_dpp((int)v, (int)v, CTRL, 0xF, 0xF, false);
    return umin2(v, (unsigned)t);
}

// Full wave64 min via DPP; wave-uniform result via readlane(63).
__device__ __forceinline__ unsigned wave_min64(unsigned v) {
    v = dpp_min<0x111>(v);  // row_shr:1
    v = dpp_min<0x112>(v);  // row_shr:2
    v = dpp_min<0x114>(v);  // row_shr:4
    v = dpp_min<0x118>(v);  // row_shr:8
    v = dpp_min<0x142>(v);  // row_bcast:15
    v = dpp_min<0x143>(v);  // row_bcast:31
    return (unsigned)__builtin_amdgcn_readlane((int)v, 63);
}

// Kernel 2: 4-wave register-resident scan (key algebra = rounds 5-7) with the
// per-round __syncthreads REPLACED by a tag-stamped LDS spin exchange:
//   slot[parity][wave] = { m1|tag , m2|tag }  (two staggered ds_write_b32)
//   spin: broadcast ds_read_b64 x4 until all 8 tags == current round tag.
// No s_barrier in the flip loop => no s_waitcnt vmcnt(0) drain => speculative
// row prefetches stay in flight across rounds (the m97 barrier-drain stall
// is structural to __syncthreads, not to our data flow). Parity buffering
// bounds wave skew to 1 round; 6-bit tag disambiguates slot reuse.
__global__ __launch_bounds__(256) void hop_seq(const float* __restrict__ W,
                                               const float* __restrict__ x,
                                               const int* __restrict__ perms,
                                               const double* __restrict__ Z0,
                                               float* __restrict__ out) {
    const int b = blockIdx.x;
    const int tid = threadIdx.x;
    const int wid = tid >> 6;
    const int lane = tid & 63;

    __shared__ int wpos[N];                               // 16 KB inverse map
    __shared__ __align__(8) volatile unsigned slotw[2][4][2];  // [parity][wave][m1,m2]

    // ---- register-resident field ----
    double zj[E];
    unsigned ymask[E];             // 0xFFFFFFFF if y>0 else 0x7FFFFFFF
    unsigned sk[E];
    {
        const double* __restrict__ zsrc = Z0 + (size_t)b * N + E * tid;
#pragma unroll
        for (int k = 0; k < E; ++k) zj[k] = zsrc[k];
        const float4* __restrict__ xs = (const float4*)(x + (size_t)b * N);
#pragma unroll
        for (int q = 0; q < 4; ++q) {
            const float4 xv = xs[4 * tid + q];
            ymask[4 * q + 0] = (xv.x > 0.f) ? 0xFFFFFFFFu : 0x7FFFFFFFu;
            ymask[4 * q + 1] = (xv.y > 0.f) ? 0xFFFFFFFFu : 0x7FFFFFFFu;
            ymask[4 * q + 2] = (xv.z > 0.f) ? 0xFFFFFFFFu : 0x7FFFFFFFu;
            ymask[4 * q + 3] = (xv.w > 0.f) ? 0xFFFFFFFFu : 0x7FFFFFFFu;
        }
    }
    const int* __restrict__ perm_b = perms + (size_t)b * T;

    float pf[E];                   // prefetched row fragment (W is immutable:
    int pf_i = -1;                 //  stale pf stays valid forever)
    unsigned r = 0;                // global round counter (never reset)

    for (int base = 0; base < T; base += WIN) {
        const int epoch = (base >> 10) + 1;
        // scatter inverse map (window = permutation slice, indices distinct)
        const int4 iv = ((const int4*)(perm_b + base))[tid];
        wpos[iv.x] = (epoch << 10) | (4 * tid + 0);
        wpos[iv.y] = (epoch << 10) | (4 * tid + 1);
        wpos[iv.z] = (epoch << 10) | (4 * tid + 2);
        wpos[iv.w] = (epoch << 10) | (4 * tid + 3);
        __syncthreads();   // infrequent (40x): full drain acceptable here
        // build static keys for the 16 owned elems
#pragma unroll
        for (int q = 0; q < 4; ++q) {
            const int4 wp = ((const int4*)wpos)[4 * tid + q];
            const int e0 = 4 * q;
            const unsigned i0 = (unsigned)(E * tid + e0);
            sk[e0 + 0] = ((wp.x >> 10) == epoch)
                ? (((unsigned)(wp.x & 1023) << 14) | ((i0 + 0) << 2) | ((ymask[e0 + 0] >> 30) & 2u)) : INFK;
            sk[e0 + 1] = ((wp.y >> 10) == epoch)
                ? (((unsigned)(wp.y & 1023) << 14) | ((i0 + 1) << 2) | ((ymask[e0 + 1] >> 30) & 2u)) : INFK;
            sk[e0 + 2] = ((wp.z >> 10) == epoch)
                ? (((unsigned)(wp.z & 1023) << 14) | ((i0 + 2) << 2) | ((ymask[e0 + 2] >> 30) & 2u)) : INFK;
            sk[e0 + 3] = ((wp.w >> 10) == epoch)
                ? (((unsigned)(wp.w & 1023) << 14) | ((i0 + 3) << 2) | ((ymask[e0 + 3] >> 30) & 2u)) : INFK;
        }

        unsigned ck = 0;
        // round-0 pure scan
        unsigned key = INFK;
#pragma unroll
        for (int k = 0; k < E; ++k) {
            const unsigned t2 = ((unsigned)__double2hiint(zj[k])) ^ ymask[k];
            const unsigned cand = (sk[k] | (unsigned)(((int)t2) >> 31)) - ck;
            key = umin2(key, cand);
        }

        for (;;) {
            const unsigned p = r & 1u;
            const unsigned tg = (r & 63u);
            const unsigned tgs = tg << 26;
            // ---- wave min via DPP; publish m1 early (m2 chain overlaps) ----
            const unsigned m1 = wave_min64(key);
            if (lane == 0) slotw[p][wid][0] = umin2(m1, LIMIT) | tgs;
            const unsigned m2 = wave_min64((key == m1) ? INFK : key);
            if (lane == 0) slotw[p][wid][1] = umin2(m2, LIMIT) | tgs;
            r++;

            // ---- spin until all 4 waves' (m1,m2) carry this round's tag ----
            unsigned s1v[4], s2v[4];
            for (;;) {
                unsigned tcheck = 0;
#pragma unroll
                for (int w = 0; w < 4; ++w) {
                    const unsigned long long v =
                        *(volatile const unsigned long long*)(&slotw[p][w][0]);
                    s1v[w] = (unsigned)v;
                    s2v[w] = (unsigned)(v >> 32);
                    tcheck |= ((s1v[w] >> 26) ^ tg) | ((s2v[w] >> 26) ^ tg);
                }
                if (tcheck == 0u) break;
            }

            // ---- exact global top-2 from the 8 payloads ----
            const unsigned p0 = s1v[0] & 0x03FFFFFFu, p1 = s1v[1] & 0x03FFFFFFu;
            const unsigned p2 = s1v[2] & 0x03FFFFFFu, p3 = s1v[3] & 0x03FFFFFFu;
            const unsigned g = umin2(umin2(p0, p1), umin2(p2, p3));
            if (g >= LIMIT) break;   // no valid future candidate (uniform)
            const unsigned q0 = (p0 == g) ? (s2v[0] & 0x03FFFFFFu) : p0;
            const unsigned q1 = (p1 == g) ? (s2v[1] & 0x03FFFFFFu) : p1;
            const unsigned q2 = (p2 == g) ? (s2v[2] & 0x03FFFFFFu) : p2;
            const unsigned q3 = (p3 == g) ? (s2v[3] & 0x03FFFFFFu) : p3;
            const unsigned g2 = umin2(umin2(q0, q1), umin2(q2, q3));

            const unsigned wk = g + ck;
            const int istar = (int)((wk >> 2) & 4095u);
            const int y1 = (int)(wk & 3u) - 1;
            const double d = (double)(-2 * y1);   // mismatch => s = -y
            const unsigned ck_old = ck;
            ck = ((wk >> 14) + 1u) << 14;

            // ---- winner row: pf hit (common) or immediate load (rare) ----
            const bool hit = (istar == pf_i);     // uniform
            float wr[E];
            const float4* __restrict__ rowp = (const float4*)(W + (size_t)istar * N) + 4 * tid;
            if (!hit) {
                const float4 a = rowp[0], c = rowp[1], e = rowp[2], f = rowp[3];
                wr[0] = a.x;  wr[1] = a.y;  wr[2] = a.z;  wr[3] = a.w;
                wr[4] = c.x;  wr[5] = c.y;  wr[6] = c.z;  wr[7] = c.w;
                wr[8] = e.x;  wr[9] = e.y;  wr[10] = e.z; wr[11] = e.w;
                wr[12] = f.x; wr[13] = f.y; wr[14] = f.z; wr[15] = f.w;
            } else {
#pragma unroll
                for (int k = 0; k < E; ++k) wr[k] = pf[k];
            }
            // ---- exact next-candidate prefetch: stays in flight across the
            //      spin (no barrier drain) and lands by next round's apply ----
            if (g2 < LIMIT) {
                const int i2 = (int)(((g2 + ck_old) >> 2) & 4095u);
                const float4* __restrict__ r2 = (const float4*)(W + (size_t)i2 * N) + 4 * tid;
                const float4 a = r2[0], c = r2[1], e = r2[2], f = r2[3];
                pf[0] = a.x;  pf[1] = a.y;  pf[2] = a.z;  pf[3] = a.w;
                pf[4] = c.x;  pf[5] = c.y;  pf[6] = c.z;  pf[7] = c.w;
                pf[8] = e.x;  pf[9] = e.y;  pf[10] = e.z; pf[11] = e.w;
                pf[12] = f.x; pf[13] = f.y; pf[14] = f.z; pf[15] = f.w;
                pf_i = i2;
            }

            // ---- owner fixup (1 thread) ----
            if (tid == (istar >> 4)) {
                const int kk = istar & 15;
#pragma unroll
                for (int k = 0; k < E; ++k)
                    if (k == kk) { ymask[k] ^= 0x80000000u; sk[k] ^= 2u; }
            }

            // ---- fused apply + scan for next winner ----
            key = INFK;
#pragma unroll
            for (int k = 0; k < E; ++k) {
                zj[k] += d * (double)wr[k];   // W[istar][istar]==0 -> owner safe
                const unsigned t2 = ((unsigned)__double2hiint(zj[k])) ^ ymask[k];
                const unsigned cand = (sk[k] | (unsigned)(((int)t2) >> 31)) - ck;
                key = umin2(key, cand);
            }
        }
    }

    // ---- output: y = +1 if ymask top bit set else -1 ----
    float4* __restrict__ os = (float4*)(out + (size_t)b * N);
#pragma unroll
    for (int q = 0; q < 4; ++q) {
        float4 o;
        o.x = (ymask[4 * q + 0] & 0x80000000u) ? 1.0f : -1.0f;
        o.y = (ymask[4 * q + 1] & 0x80000000u) ? 1.0f : -1.0f;
        o.z = (ymask[4 * q + 2] & 0x80000000u) ? 1.0f : -1.0f;
        o.w = (ymask[4 * q + 3] & 0x80000000u) ? 1.0f : -1.0f;
        os[4 * tid + q] = o;
    }
}

extern "C" void kernel_launch(void* const* d_in, const int* in_sizes, int n_in,
                              void* d_out, int out_size, void* d_ws, size_t ws_size,
                              hipStream_t stream) {
    const float* x = (const float*)d_in[0];      // [B, N] f32, bipolar
    const float* W = (const float*)d_in[1];      // [N, N] f32, symmetric, zero diag
    const int* perms = (const int*)d_in[2];      // [B, ITERS, N] i32
    float* out = (float*)d_out;                  // [B, N] f32
    double* Z0 = (double*)d_ws;                  // B*N doubles = 256 KB scratch

    hipLaunchKernelGGL(z0_gemv, dim3(N), dim3(256), 0, stream, W, x, Z0);
    hipLaunchKernelGGL(hop_seq, dim3(B), dim3(NT), 0, stream, W, x, perms, Z0, out);
}

// Round 10
// 3038.297 us; speedup vs baseline: 1.1534x; 1.1534x over previous
//
#include <hip/hip_runtime.h>
#include <hip/hip_bf16.h>

#define N 4096
#define B 8
#define ITERS 10
#define T (ITERS * N)
#define NT 256          // 4 waves
#define E 16            // field elements per thread
#define WIN 1024
#define INFK 0xFFFFFFFFu
#define LIMIT 0x01000000u

// Kernel 1: Z0[b][i] = sum_j W[i][j] * x[b][j], accumulated in double.
// UNCHANGED (decision-identical trajectory vs rounds 1-8).
__global__ __launch_bounds__(256) void z0_gemv(const float* __restrict__ W,
                                               const float* __restrict__ x,
                                               double* __restrict__ Z0) {
    const int i = blockIdx.x;
    const int tid = threadIdx.x;
    const float* __restrict__ row = W + (size_t)i * N;

    double acc[B];
#pragma unroll
    for (int b = 0; b < B; ++b) acc[b] = 0.0;

    for (int j = tid; j < N; j += 256) {
        const double w = (double)row[j];
#pragma unroll
        for (int b = 0; b < B; ++b) acc[b] += w * (double)x[b * N + j];
    }

    __shared__ double red[256 * B];  // 16 KB
#pragma unroll
    for (int b = 0; b < B; ++b) red[tid * B + b] = acc[b];
    __syncthreads();

    for (int s = 128; s > 0; s >>= 1) {
        if (tid < s) {
#pragma unroll
            for (int b = 0; b < B; ++b) red[tid * B + b] += red[(tid + s) * B + b];
        }
        __syncthreads();
    }
    if (tid < B) Z0[(size_t)tid * N + i] = red[tid];
}

__device__ __forceinline__ unsigned umin2(unsigned a, unsigned b) { return a < b ? a : b; }

template <int CTRL>
__device__ __forceinline__ unsigned dpp_min(unsigned v) {
    const int t = __builtin_amdgcn_update_dpp((int)v, (int)v, CTRL, 0xF, 0xF, false);
    return umin2(v, (unsigned)t);
}

// Full wave64 min via DPP; wave-uniform result via readlane(63).
__device__ __forceinline__ unsigned wave_min64(unsigned v) {
    v = dpp_min<0x111>(v);  // row_shr:1
    v = dpp_min<0x112>(v);  // row_shr:2
    v = dpp_min<0x114>(v);  // row_shr:4
    v = dpp_min<0x118>(v);  // row_shr:8
    v = dpp_min<0x142>(v);  // row_bcast:15
    v = dpp_min<0x143>(v);  // row_bcast:31
    return (unsigned)__builtin_amdgcn_readlane((int)v, 63);
}

// Wave top-3: m1 exact; m2/m3 may miss same-lane runners-up -> used as
// predictions only, always verified before commit.
__device__ __forceinline__ void wave_top3(unsigned key, unsigned& m1, unsigned& m2, unsigned& m3) {
    m1 = wave_min64(key);
    const unsigned k2 = (key == m1) ? INFK : key;
    m2 = wave_min64(k2);
    const unsigned k3 = (k2 == m2) ? INFK : k2;
    m3 = wave_min64(k3);
}

// Min candidate (relative to base) over the 16 owned elems. Valid iff
// in-window (sk finite), pos >= base (else wraps high), sign(z) == -y
// (else sign-mask widens to INF).
__device__ __forceinline__ unsigned scan16(const double* zz, const unsigned* ym,
                                           const unsigned* sk, unsigned base) {
    unsigned key = INFK;
#pragma unroll
    for (int k = 0; k < E; ++k) {
        const unsigned t2 = ((unsigned)__double2hiint(zz[k])) ^ ym[k];
        const unsigned cand = (sk[k] | (unsigned)(((int)t2) >> 31)) - base;
        key = umin2(key, cand);
    }
    return key;
}

// Exact top-3 of the 12 published per-wave {t1,t2,t3} (valid keys unique).
__device__ __forceinline__ void top3of12(const unsigned* a, const unsigned* bb, const unsigned* cc,
                                         unsigned& g1, unsigned& g2, unsigned& g3) {
    g1 = umin2(umin2(a[0], a[1]), umin2(a[2], a[3]));
    unsigned ca[4], cb[4];
#pragma unroll
    for (int w = 0; w < 4; ++w) ca[w] = (a[w] == g1) ? bb[w] : a[w];
    g2 = umin2(umin2(ca[0], ca[1]), umin2(ca[2], ca[3]));
#pragma unroll
    for (int w = 0; w < 4; ++w)
        cb[w] = (a[w] == g1) ? ((bb[w] == g2) ? cc[w] : bb[w])
                             : ((a[w] == g2) ? bb[w] : a[w]);
    g3 = umin2(umin2(cb[0], cb[1]), umin2(cb[2], cb[3]));
}

__device__ __forceinline__ unsigned satabs(unsigned rel, unsigned base) {
    return (rel >= LIMIT) ? INFK : (rel + base);   // window-absolute, < LIMIT
}

__device__ __forceinline__ void copy16(float* dst, const float* src) {
#pragma unroll
    for (int k = 0; k < E; ++k) dst[k] = src[k];
}

__device__ __forceinline__ void load_row(const float* __restrict__ W, int idx, int tid, float* dst) {
    const float4* __restrict__ rp = (const float4*)(W + (size_t)idx * N) + 4 * tid;
    const float4 a = rp[0], c = rp[1], e = rp[2], f = rp[3];
    dst[0] = a.x;  dst[1] = a.y;  dst[2] = a.z;  dst[3] = a.w;
    dst[4] = c.x;  dst[5] = c.y;  dst[6] = c.z;  dst[7] = c.w;
    dst[8] = e.x;  dst[9] = e.y;  dst[10] = e.z; dst[11] = e.w;
    dst[12] = f.x; dst[13] = f.y; dst[14] = f.z; dst[15] = f.w;
}

// Fetch this thread's 64B fragment of row idx: 3-entry register cache
// (W immutable -> entries never stale), else direct coalesced load.
__device__ __forceinline__ void get_row(const float* __restrict__ W, int idx, int tid,
                                        int pfa_i, const float* pfa,
                                        int pfb_i, const float* pfb,
                                        int pfc_i, const float* pfc, float* dst) {
    if (idx == pfa_i)      copy16(dst, pfa);
    else if (idx == pfb_i) copy16(dst, pfb);
    else if (idx == pfc_i) copy16(dst, pfc);
    else load_row(W, idx, tid, dst);
}

// Kernel 2: depth-2 speculative flip pipeline. Register-resident field
// (r5-r7 key algebra). Each round: apply pipelined flip A (exact), apply
// B (exact-top-2 prediction) speculatively into zjS; ONE barrier exchange
// carries the verification min (keys after A, pos>pA) and the next
// pipeline's top-3 (keys after A+B, pos>pB). Confirmed -> 2 flips per
// barrier and the tail top-3 is already the next round's reduce; rows for
// the next 3 candidates prefetched a full round before their use (so the
// barrier's vmcnt drain hits completed loads). Mispredict -> commit A +
// exact true successor C, reboot pipeline with one recovery exchange.
__global__ __launch_bounds__(256, 1) void hop_seq(const float* __restrict__ W,
                                                  const float* __restrict__ x,
                                                  const int* __restrict__ perms,
                                                  const double* __restrict__ Z0,
                                                  float* __restrict__ out) {
    const int b = blockIdx.x;
    const int tid = threadIdx.x;
    const int wid = tid >> 6;
    const int lane = tid & 63;

    __shared__ int wpos[N];              // 16 KB epoch-tagged inverse map
    __shared__ uint4 slots[2][4];        // [parity][wave] = {v, t1, t2, t3}

    double zj[E];
    unsigned ymask[E];                   // 0xFFFFFFFF if y>0 else 0x7FFFFFFF
    unsigned sk[E];
    {
        const double* __restrict__ zsrc = Z0 + (size_t)b * N + E * tid;
#pragma unroll
        for (int k = 0; k < E; ++k) zj[k] = zsrc[k];
        const float4* __restrict__ xs = (const float4*)(x + (size_t)b * N);
#pragma unroll
        for (int q = 0; q < 4; ++q) {
            const float4 xv = xs[4 * tid + q];
            ymask[4 * q + 0] = (xv.x > 0.f) ? 0xFFFFFFFFu : 0x7FFFFFFFu;
            ymask[4 * q + 1] = (xv.y > 0.f) ? 0xFFFFFFFFu : 0x7FFFFFFFu;
            ymask[4 * q + 2] = (xv.z > 0.f) ? 0xFFFFFFFFu : 0x7FFFFFFFu;
            ymask[4 * q + 3] = (xv.w > 0.f) ? 0xFFFFFFFFu : 0x7FFFFFFFu;
        }
    }
    const int* __restrict__ perm_b = perms + (size_t)b * T;

    float pfa[E], pfb[E], pfc[E];
    int pfa_i = -1, pfb_i = -1, pfc_i = -1;
    unsigned r = 0;                      // exchange parity counter (never reset)

    for (int base = 0; base < T; base += WIN) {
        const int epoch = (base >> 10) + 1;
        const int4 iv = ((const int4*)(perm_b + base))[tid];
        wpos[iv.x] = (epoch << 10) | (4 * tid + 0);
        wpos[iv.y] = (epoch << 10) | (4 * tid + 1);
        wpos[iv.z] = (epoch << 10) | (4 * tid + 2);
        wpos[iv.w] = (epoch << 10) | (4 * tid + 3);
        __syncthreads();
#pragma unroll
        for (int q = 0; q < 4; ++q) {
            const int4 wp = ((const int4*)wpos)[4 * tid + q];
            const int e0 = 4 * q;
            const unsigned i0 = (unsigned)(E * tid + e0);
            sk[e0 + 0] = ((wp.x >> 10) == epoch)
                ? (((unsigned)(wp.x & 1023) << 14) | ((i0 + 0) << 2) | ((ymask[e0 + 0] >> 30) & 2u)) : INFK;
            sk[e0 + 1] = ((wp.y >> 10) == epoch)
                ? (((unsigned)(wp.y & 1023) << 14) | ((i0 + 1) << 2) | ((ymask[e0 + 1] >> 30) & 2u)) : INFK;
            sk[e0 + 2] = ((wp.z >> 10) == epoch)
                ? (((unsigned)(wp.z & 1023) << 14) | ((i0 + 2) << 2) | ((ymask[e0 + 2] >> 30) & 2u)) : INFK;
            sk[e0 + 3] = ((wp.w >> 10) == epoch)
                ? (((unsigned)(wp.w & 1023) << 14) | ((i0 + 3) << 2) | ((ymask[e0 + 3] >> 30) & 2u)) : INFK;
        }

        unsigned ck = 0;                       // consumed-prefix base (<<14)
        unsigned g1 = INFK, g2 = INFK, g3 = INFK;  // pipeline keys (window-abs)
        bool have = false;

        for (;;) {
            if (!have) {
                // ---- boot/recovery exchange: fresh reduce of keys(zj) ----
                const unsigned key = scan16(zj, ymask, sk, ck);
                unsigned m1, m2, m3;
                wave_top3(key, m1, m2, m3);
                const unsigned p = r & 1u; r++;
                if (lane == 0) slots[p][wid] = make_uint4(INFK, m1, m2, m3);
                __syncthreads();
                const uint4 s0 = slots[p][0], s1 = slots[p][1];
                const uint4 s2 = slots[p][2], s3 = slots[p][3];
                const unsigned ta[4] = {s0.y, s1.y, s2.y, s3.y};
                const unsigned tb[4] = {s0.z, s1.z, s2.z, s3.z};
                const unsigned tc[4] = {s0.w, s1.w, s2.w, s3.w};
                unsigned r1, r2, r3;
                top3of12(ta, tb, tc, r1, r2, r3);
                g1 = satabs(r1, ck); g2 = satabs(r2, ck); g3 = satabs(r3, ck);
                have = true;
            }
            if (g1 >= LIMIT) break;      // window done (uniform)

            // ---- flip A (exact, committed) ----
            const int iA = (int)((g1 >> 2) & 4095u);
            const double dA = (double)(-2 * ((int)(g1 & 3u) - 1));
            float wA[E];
            get_row(W, iA, tid, pfa_i, pfa, pfb_i, pfb, pfc_i, pfc, wA);
#pragma unroll
            for (int k = 0; k < E; ++k) zj[k] += dA * (double)wA[k];
            if (tid == (iA >> 4)) {
                const int kk = iA & 15;
#pragma unroll
                for (int k = 0; k < E; ++k) if (k == kk) ymask[k] ^= 0x80000000u;
            }
            const unsigned ckA = ((g1 >> 14) + 1u) << 14;
            const bool haveB = (g2 < LIMIT);     // uniform

            // ---- speculative flip B + scans ----
            const unsigned keyV = scan16(zj, ymask, sk, ckA);  // verification
            double zjS[E];
            float wB[E];
            int iB = 0; unsigned ckB = ckA;
            unsigned vm, t1, t2, t3;
            if (haveB) {
                iB = (int)((g2 >> 2) & 4095u);
                const double dB = (double)(-2 * ((int)(g2 & 3u) - 1));
                get_row(W, iB, tid, pfa_i, pfa, pfb_i, pfb, pfc_i, pfc, wB);
#pragma unroll
                for (int k = 0; k < E; ++k) zjS[k] = zj[k] + dB * (double)wB[k];
                ckB = ((g2 >> 14) + 1u) << 14;
                const unsigned keyT = scan16(zjS, ymask, sk, ckB);
                vm = wave_min64(keyV);
                wave_top3(keyT, t1, t2, t3);
            } else {
                wave_top3(keyV, t1, t2, t3);
                vm = INFK;
            }

            // ---- single exchange: {vm, t1, t2, t3} ----
            const unsigned p = r & 1u; r++;
            if (lane == 0) slots[p][wid] = make_uint4(vm, t1, t2, t3);
            __syncthreads();
            const uint4 s0 = slots[p][0], s1 = slots[p][1];
            const uint4 s2 = slots[p][2], s3 = slots[p][3];
            const unsigned gV = umin2(umin2(s0.x, s1.x), umin2(s2.x, s3.x));
            const unsigned ta[4] = {s0.y, s1.y, s2.y, s3.y};
            const unsigned tb[4] = {s0.z, s1.z, s2.z, s3.z};
            const unsigned tc[4] = {s0.w, s1.w, s2.w, s3.w};
            unsigned rT1, rT2, rT3;
            top3of12(ta, tb, tc, rT1, rT2, rT3);

            if (!haveB) {
                // committed A only; pipeline = verification-scan top-3 (g1' exact)
                ck = ckA;
                g1 = satabs(rT1, ckA); g2 = satabs(rT2, ckA); g3 = satabs(rT3, ckA);
            } else if (gV + ckA == g2) {
                // ---- confirmed: commit B; tails are already the next reduce ----
                ck = ckB;
                g1 = satabs(rT1, ckB); g2 = satabs(rT2, ckB); g3 = satabs(rT3, ckB);
                // prefetch next candidates' rows first (longest latency path)
                if (g1 < LIMIT) { pfa_i = (int)((g1 >> 2) & 4095u); load_row(W, pfa_i, tid, pfa); }
                if (g2 < LIMIT) { pfb_i = (int)((g2 >> 2) & 4095u); load_row(W, pfb_i, tid, pfb); }
                if (g3 < LIMIT) { pfc_i = (int)((g3 >> 2) & 4095u); load_row(W, pfc_i, tid, pfc); }
#pragma unroll
                for (int k = 0; k < E; ++k) zj[k] = zjS[k];
                if (tid == (iB >> 4)) {
                    const int kk = iB & 15;
#pragma unroll
                    for (int k = 0; k < E; ++k) if (k == kk) ymask[k] ^= 0x80000000u;
                }
            } else if (gV >= LIMIT) {
                break;   // B healed by A, nothing else remains -> window done
            } else {
                // ---- mispredict: true successor is C = gV (exact) ----
                const unsigned gC = gV + ckA;
                const int iC = (int)((gC >> 2) & 4095u);
                const double dC = (double)(-2 * ((int)(gC & 3u) - 1));
                float wC[E];
                get_row(W, iC, tid, pfa_i, pfa, pfb_i, pfb, pfc_i, pfc, wC);
#pragma unroll
                for (int k = 0; k < E; ++k) zj[k] += dC * (double)wC[k];
                if (tid == (iC >> 4)) {
                    const int kk = iC & 15;
#pragma unroll
                    for (int k = 0; k < E; ++k) if (k == kk) ymask[k] ^= 0x80000000u;
                }
                ck = ((gC >> 14) + 1u) << 14;
                have = false;            // reboot pipeline next iteration
            }
        }
    }

    float4* __restrict__ os = (float4*)(out + (size_t)b * N);
#pragma unroll
    for (int q = 0; q < 4; ++q) {
        float4 o;
        o.x = (ymask[4 * q + 0] & 0x80000000u) ? 1.0f : -1.0f;
        o.y = (ymask[4 * q + 1] & 0x80000000u) ? 1.0f : -1.0f;
        o.z = (ymask[4 * q + 2] & 0x80000000u) ? 1.0f : -1.0f;
        o.w = (ymask[4 * q + 3] & 0x80000000u) ? 1.0f : -1.0f;
        os[4 * tid + q] = o;
    }
}

extern "C" void kernel_launch(void* const* d_in, const int* in_sizes, int n_in,
                              void* d_out, int out_size, void* d_ws, size_t ws_size,
                              hipStream_t stream) {
    const float* x = (const float*)d_in[0];      // [B, N] f32, bipolar
    const float* W = (const float*)d_in[1];      // [N, N] f32, symmetric, zero diag
    const int* perms = (const int*)d_in[2];      // [B, ITERS, N] i32
    float* out = (float*)d_out;                  // [B, N] f32
    double* Z0 = (double*)d_ws;                  // B*N doubles = 256 KB scratch

    hipLaunchKernelGGL(z0_gemv, dim3(N), dim3(256), 0, stream, W, x, Z0);
    hipLaunchKernelGGL(hop_seq, dim3(B), dim3(NT), 0, stream, W, x, perms, Z0, out);
}